// Round 5
// baseline (144.650 us; speedup 1.0000x reference)
//
#include <hip/hip_runtime.h>

#define POOL 7
#define NUM_ROIS 300
#define FH 200
#define FW 200
#define FC 512

typedef float f4 __attribute__((ext_vector_type(4)));

// One block per (roi, py, px) cell. 128 threads x f4 = 512 channels.
__global__ __launch_bounds__(128) void roi_pool_kernel(
    const float* __restrict__ feat,   // (FH, FW, FC) fp32, NHWC
    const int*   __restrict__ rois,   // (NUM_ROIS, 4) int32: x0,y0,w,h
    float*       __restrict__ out)    // (NUM_ROIS, POOL, POOL, FC) fp32
{
    const int cell = blockIdx.x;                // 0 .. NUM_ROIS*49-1
    const int r    = cell / (POOL * POOL);
    const int pp   = cell - r * (POOL * POOL);
    const int py   = pp / POOL;
    const int px   = pp - py * POOL;

    const int x0 = rois[4 * r + 0];
    const int y0 = rois[4 * r + 1];
    const int w  = rois[4 * r + 2];
    const int h  = rois[4 * r + 3];

    // Match reference arithmetic: sy = py*(h/7), sx = px*(w/7) in fp32.
    const float sy = (float)py * ((float)h / 7.0f);
    const float sx = (float)px * ((float)w / 7.0f);
    const int y_lo = (int)floorf(sy);
    const int x_lo = (int)floorf(sx);
    const int y_hi = min(y_lo + 1, h - 1);
    const int x_hi = min(x_lo + 1, w - 1);
    const float fy = sy - (float)y_lo;
    const float fx = sx - (float)x_lo;

    const float w00 = (1.0f - fy) * (1.0f - fx);
    const float w01 = (1.0f - fy) * fx;
    const float w10 = fy * (1.0f - fx);
    const float w11 = fy * fx;

    const size_t row_lo = (size_t)(y0 + y_lo) * FW;
    const size_t row_hi = (size_t)(y0 + y_hi) * FW;
    const f4* __restrict__ f00 = (const f4*)(feat + (row_lo + (x0 + x_lo)) * FC);
    const f4* __restrict__ f01 = (const f4*)(feat + (row_lo + (x0 + x_hi)) * FC);
    const f4* __restrict__ f10 = (const f4*)(feat + (row_hi + (x0 + x_lo)) * FC);
    const f4* __restrict__ f11 = (const f4*)(feat + (row_hi + (x0 + x_hi)) * FC);
    f4* __restrict__ o = (f4*)(out + (size_t)cell * FC);

    const int t = threadIdx.x;                  // 0..127, one f4 each
    const f4 v00 = f00[t];
    const f4 v01 = f01[t];
    const f4 v10 = f10[t];
    const f4 v11 = f11[t];

    const f4 res = v00 * w00 + v01 * w01 + v10 * w10 + v11 * w11;
    // Write-once stream: non-temporal, don't evict feat from L2/L3.
    __builtin_nontemporal_store(res, &o[t]);
}

extern "C" void kernel_launch(void* const* d_in, const int* in_sizes, int n_in,
                              void* d_out, int out_size, void* d_ws, size_t ws_size,
                              hipStream_t stream) {
    const float* feat = (const float*)d_in[0];  // (1,200,200,512) fp32
    const int*   rois = (const int*)d_in[1];    // (1,300,4) int32
    float*       out  = (float*)d_out;          // (1,300,7,7,512) fp32

    const int n_cells = NUM_ROIS * POOL * POOL; // 14700
    // MEASUREMENT PROBE: identical kernel twice (idempotent, same output).
    // dur_us delta vs round 1/3 (~124 us) == true per-launch kernel time,
    // since round 4 proved feat is already L3-resident before launch.
    roi_pool_kernel<<<n_cells, 128, 0, stream>>>(feat, rois, out);
    roi_pool_kernel<<<n_cells, 128, 0, stream>>>(feat, rois, out);
}

// Round 6
// 121.604 us; speedup vs baseline: 1.1895x; 1.1895x over previous
//
#include <hip/hip_runtime.h>

#define POOL 7
#define NUM_ROIS 300
#define FH 200
#define FW 200
#define FC 512
#define N_CELLS (NUM_ROIS * POOL * POOL)   // 14700

typedef float f4 __attribute__((ext_vector_type(4)));

// 256-thread block handles 2 consecutive (roi,py,px) cells: threads 0..127 ->
// cell 2b, threads 128..255 -> cell 2b+1. Per-wave uniform control flow.
// Kernel is L3/fabric-throughput bound (measured 7.2 TB/s combined effective,
// T ~= 20.5 us); this variant halves block count for dispatch overhead + minor
// L1 reuse between paired cells.
__global__ __launch_bounds__(256) void roi_pool_kernel(
    const float* __restrict__ feat,   // (FH, FW, FC) fp32, NHWC
    const int*   __restrict__ rois,   // (NUM_ROIS, 4) int32: x0,y0,w,h
    float*       __restrict__ out)    // (NUM_ROIS, POOL, POOL, FC) fp32
{
    const int cell = blockIdx.x * 2 + (threadIdx.x >> 7);   // wave-uniform
    const int t    = threadIdx.x & 127;                     // 0..127 within cell

    const int r    = cell / (POOL * POOL);
    const int pp   = cell - r * (POOL * POOL);
    const int py   = pp / POOL;
    const int px   = pp - py * POOL;

    const int x0 = rois[4 * r + 0];
    const int y0 = rois[4 * r + 1];
    const int w  = rois[4 * r + 2];
    const int h  = rois[4 * r + 3];

    // Match reference arithmetic: sy = py*(h/7), sx = px*(w/7) in fp32.
    const float sy = (float)py * ((float)h / 7.0f);
    const float sx = (float)px * ((float)w / 7.0f);
    const int y_lo = (int)floorf(sy);
    const int x_lo = (int)floorf(sx);
    const int y_hi = min(y_lo + 1, h - 1);
    const int x_hi = min(x_lo + 1, w - 1);
    const float fy = sy - (float)y_lo;
    const float fx = sx - (float)x_lo;

    const float w00 = (1.0f - fy) * (1.0f - fx);
    const float w01 = (1.0f - fy) * fx;
    const float w10 = fy * (1.0f - fx);
    const float w11 = fy * fx;

    const size_t row_lo = (size_t)(y0 + y_lo) * FW;
    const size_t row_hi = (size_t)(y0 + y_hi) * FW;
    const f4* __restrict__ f00 = (const f4*)(feat + (row_lo + (x0 + x_lo)) * FC);
    const f4* __restrict__ f01 = (const f4*)(feat + (row_lo + (x0 + x_hi)) * FC);
    const f4* __restrict__ f10 = (const f4*)(feat + (row_hi + (x0 + x_lo)) * FC);
    const f4* __restrict__ f11 = (const f4*)(feat + (row_hi + (x0 + x_hi)) * FC);
    f4* __restrict__ o = (f4*)(out + (size_t)cell * FC);

    const f4 v00 = f00[t];
    const f4 v01 = f01[t];
    const f4 v10 = f10[t];
    const f4 v11 = f11[t];

    const f4 res = v00 * w00 + v01 * w01 + v10 * w10 + v11 * w11;
    // Write-once stream: non-temporal, don't evict feat from L2/L3.
    __builtin_nontemporal_store(res, &o[t]);
}

extern "C" void kernel_launch(void* const* d_in, const int* in_sizes, int n_in,
                              void* d_out, int out_size, void* d_ws, size_t ws_size,
                              hipStream_t stream) {
    const float* feat = (const float*)d_in[0];  // (1,200,200,512) fp32
    const int*   rois = (const int*)d_in[1];    // (1,300,4) int32
    float*       out  = (float*)d_out;          // (1,300,7,7,512) fp32

    roi_pool_kernel<<<N_CELLS / 2, 256, 0, stream>>>(feat, rois, out);
}